// Round 4
// baseline (330.070 us; speedup 1.0000x reference)
//
#include <hip/hip_runtime.h>
#include <stdint.h>

// Decomposition (unchanged):
//   UV[n][j] = z[n] . Wcat[:,j] (+ b1[j] for j<128), stored bf16, j in 0..255
//     where Wcat[k][j] = (j<128) ? W1[j][k] : W1[j-128][64+k]
//   out[e] = b2 + sum_j W2[j] * relu(UV[row[e]][j] + UV[col[e]][128+j])
//
// R4 fix: R3 gave each WAVE its own tile but kept per-wave column slicing
// (w*64+...), so each node row got only 1/4 of its cols written (absmax 3.16).
// Now all 4 waves of a block share one tile; wave w covers cols w*64..w*64+63.
// Structure stays barrier-free / LDS-free: direct dwordx4 z loads (L1 absorbs
// the 4x intra-block redundancy), W fragments in registers across a grid-stride
// tile loop, packed 8B UV stores.

typedef __attribute__((ext_vector_type(8))) short bf16x8;
typedef __attribute__((ext_vector_type(4))) float f32x4;

__device__ inline unsigned short f2bf(float f) {
    uint32_t u = __builtin_bit_cast(uint32_t, f);
    uint32_t r = (u + 0x7FFFu + ((u >> 16) & 1u)) >> 16;  // RNE
    return (unsigned short)r;
}

__device__ inline bf16x8 pack8(float4 a, float4 b) {
    bf16x8 o;
    o[0] = (short)f2bf(a.x); o[1] = (short)f2bf(a.y);
    o[2] = (short)f2bf(a.z); o[3] = (short)f2bf(a.w);
    o[4] = (short)f2bf(b.x); o[5] = (short)f2bf(b.y);
    o[6] = (short)f2bf(b.z); o[7] = (short)f2bf(b.w);
    return o;
}

// ---------------- Kernel 1: node precompute via MFMA, barrier-free ------------
__global__ __launch_bounds__(256) void node_precompute_mfma(
    const float* __restrict__ z, const float* __restrict__ W1,
    const float* __restrict__ b1, unsigned short* __restrict__ UV,
    int n_nodes)
{
    const int tid = threadIdx.x;
    const int w  = tid >> 6;    // wave 0..3 -> owns output cols w*64..w*64+63
    const int l  = tid & 63;
    const int lm = l & 15;      // free-dim sublane
    const int q  = l >> 4;      // quad 0..3

    // ---- W fragments (A slot): loaded ONCE, vectorized. ----
    // A-slot free index (lm) -> output col c; k chunk = kh*32 + q*8 + j.
    bf16x8 wfrag[4][2];
    float4 bias[4];
#pragma unroll
    for (int nt = 0; nt < 4; ++nt) {
        const int c = w * 64 + nt * 16 + lm;               // output col 0..255
        const float* wrow = (c < 128) ? (W1 + (size_t)c * 128)
                                      : (W1 + (size_t)(c - 128) * 128 + 64);
#pragma unroll
        for (int kh = 0; kh < 2; ++kh) {
            const int k0 = kh * 32 + q * 8;
            float4 w0 = *(const float4*)(wrow + k0);
            float4 w1 = *(const float4*)(wrow + k0 + 4);
            wfrag[nt][kh] = pack8(w0, w1);
        }
        // this lane's 4 output cols in C/D: cb..cb+3 (never straddles 128)
        const int cb = w * 64 + nt * 16 + q * 4;
        bias[nt] = (cb < 128) ? *(const float4*)&b1[cb]
                              : make_float4(0.f, 0.f, 0.f, 0.f);
    }

    const int ntiles = (n_nodes + 15) >> 4;

    // Grid-stride over tiles; ALL 4 waves of the block process the SAME tile
    // (each covering a different 64-col slice -> full 256-col coverage).
    for (int tile = blockIdx.x; tile < ntiles; tile += gridDim.x) {
        const int node = tile * 16 + lm;   // B-slot free index -> node
        bf16x8 zfrag[2];
        if (node < n_nodes) {
            const float* zp = z + (size_t)node * 64;
#pragma unroll
            for (int kh = 0; kh < 2; ++kh) {
                float4 z0 = *(const float4*)(zp + kh * 32 + q * 8);
                float4 z1 = *(const float4*)(zp + kh * 32 + q * 8 + 4);
                zfrag[kh] = pack8(z0, z1);
            }
        } else {
            zfrag[0] = (bf16x8){0,0,0,0,0,0,0,0};
            zfrag[1] = (bf16x8){0,0,0,0,0,0,0,0};
        }

        f32x4 acc[4];
#pragma unroll
        for (int nt = 0; nt < 4; ++nt) acc[nt] = (f32x4){0.f, 0.f, 0.f, 0.f};
#pragma unroll
        for (int kh = 0; kh < 2; ++kh)
#pragma unroll
            for (int nt = 0; nt < 4; ++nt)
                acc[nt] = __builtin_amdgcn_mfma_f32_16x16x32_bf16(
                    wfrag[nt][kh], zfrag[kh], acc[nt], 0, 0, 0);

        // epilogue: lane (q,lm) reg r = [node=tile*16+lm][col=w*64+nt*16+q*4+r]
        if (node < n_nodes) {
            unsigned short* up = UV + (size_t)node * 256;
#pragma unroll
            for (int nt = 0; nt < 4; ++nt) {
                uint2 p;
                p.x = (uint32_t)f2bf(acc[nt][0] + bias[nt].x)
                    | ((uint32_t)f2bf(acc[nt][1] + bias[nt].y) << 16);
                p.y = (uint32_t)f2bf(acc[nt][2] + bias[nt].z)
                    | ((uint32_t)f2bf(acc[nt][3] + bias[nt].w) << 16);
                *(uint2*)(up + w * 64 + nt * 16 + q * 4) = p;   // 8B packed store
            }
        }
    }
}

// ---------------- Kernel 2: per-edge gather + relu + dot (unchanged) ----------
__device__ inline float acc2(uint32_t u, uint32_t v, float w0, float w1, float s) {
    float ul = __builtin_bit_cast(float, u << 16);
    float uh = __builtin_bit_cast(float, u & 0xFFFF0000u);
    float vl = __builtin_bit_cast(float, v << 16);
    float vh = __builtin_bit_cast(float, v & 0xFFFF0000u);
    s = fmaf(fmaxf(ul + vl, 0.f), w0, s);
    s = fmaf(fmaxf(uh + vh, 0.f), w1, s);
    return s;
}

__global__ __launch_bounds__(256) void edge_kernel(
    const unsigned short* __restrict__ UV,
    const int* __restrict__ row, const int* __restrict__ col,
    const float* __restrict__ W2, const float* __restrict__ b2,
    float* __restrict__ out, int E)
{
    const int sub = threadIdx.x & 15;           // lane within 16-lane edge-group
    const float4 w2a = *(const float4*)&W2[sub * 8];
    const float4 w2b = *(const float4*)&W2[sub * 8 + 4];
    const float bb = b2[0];

    int g = blockIdx.x * 16 + (threadIdx.x >> 4);
    const int stride = gridDim.x * 16;

    for (; g < E; g += stride) {
        const int r = row[g];
        const int c = col[g];
        uint4 uu = *(const uint4*)(UV + (size_t)r * 256 + sub * 8);          // U half
        uint4 vv = *(const uint4*)(UV + (size_t)c * 256 + 128 + sub * 8);    // V half
        float s = 0.f;
        s = acc2(uu.x, vv.x, w2a.x, w2a.y, s);
        s = acc2(uu.y, vv.y, w2a.z, w2a.w, s);
        s = acc2(uu.z, vv.z, w2b.x, w2b.y, s);
        s = acc2(uu.w, vv.w, w2b.z, w2b.w, s);
        s += __shfl_xor(s, 1, 16);
        s += __shfl_xor(s, 2, 16);
        s += __shfl_xor(s, 4, 16);
        s += __shfl_xor(s, 8, 16);
        if (sub == 0) out[g] = s + bb;
    }
}

extern "C" void kernel_launch(void* const* d_in, const int* in_sizes, int n_in,
                              void* d_out, int out_size, void* d_ws, size_t ws_size,
                              hipStream_t stream) {
    const float* z   = (const float*)d_in[0];
    const int*   row = (const int*)d_in[1];
    const int*   col = (const int*)d_in[2];
    const float* W1  = (const float*)d_in[3];
    const float* b1  = (const float*)d_in[4];
    const float* W2  = (const float*)d_in[5];
    const float* b2  = (const float*)d_in[6];
    float* out = (float*)d_out;

    const int n_nodes = in_sizes[0] / 64;   // z is [N, 64]
    const int E = in_sizes[1];

    unsigned short* UV = (unsigned short*)d_ws;  // [n_nodes][256] bf16 = 51.2 MB

    const int ntiles = (n_nodes + 15) >> 4;
    const int nblocks = (ntiles < 1024) ? ntiles : 1024;
    node_precompute_mfma<<<nblocks, 256, 0, stream>>>(z, W1, b1, UV, n_nodes);

    edge_kernel<<<4096, 256, 0, stream>>>(UV, row, col, W2, b2, out, E);
}